// Round 10
// baseline (120.689 us; speedup 1.0000x reference)
//
#include <hip/hip_runtime.h>
#include <math.h>

#define DIM    512
#define REDUC  64
#define T_FULL 4096
#define NB     32
#define SR     10
#define N_SAMP 408     // t = 0,10,...,4070
#define N_LOC  20
#define N_ROWS 428     // per batch: 408 sampled + 20 local
#define EPS    1e-5f

#define RPB   32       // rows per block (2 M-tiles of 16)
#define BPB   14       // blocks per batch (block 13: 12 local-only rows)
#define NPART 13       // blocks containing sampled rows
#define POISON 0xAAAAAAAAu

typedef short bf16x8 __attribute__((ext_vector_type(8)));   // 8 bf16 in 4 VGPRs
typedef float f32x4  __attribute__((ext_vector_type(4)));

union Frag { bf16x8 v; uint4 u; };

__device__ __forceinline__ unsigned bf16_rne(float f) {     // round-nearest-even
    unsigned u = __float_as_uint(f);
    return (u + 0x7fffu + ((u >> 16) & 1u)) >> 16;
}
__device__ __forceinline__ unsigned pack2(float lo, float hi) {
    return bf16_rne(lo) | (bf16_rne(hi) << 16);
}
// low-residual pack: bf16(a - f32(bf16(a))) for two values
__device__ __forceinline__ unsigned pack2_lo(float a, float b) {
    float fa = __uint_as_float(bf16_rne(a) << 16);
    float fb = __uint_as_float(bf16_rne(b) << 16);
    return bf16_rne(a - fa) | (bf16_rne(b - fb) << 16);
}

// coherent (agent-scope, L1-bypassing) accessors for cross-block data
__device__ __forceinline__ void coh_store(float* p, float v) {
    __hip_atomic_store(p, v, __ATOMIC_RELAXED, __HIP_MEMORY_SCOPE_AGENT);
}
__device__ __forceinline__ float coh_load(const float* p) {
    return __hip_atomic_load(p, __ATOMIC_RELAXED, __HIP_MEMORY_SCOPE_AGENT);
}

// Phase-1 / phase-2 LDS overlay (~105 KB; 1 block/CU)
struct P1 {
    Frag  w1[16 * 4 * 64];     // W1 B-frags: [sg][tile][lane]      64 KB
    Frag  abuf[8][256];        // x-tile bf16 A-frags               32 KB
    float comp[RPB][66];       // C tile (+2 pad)                  8.4 KB
    float pmax[4][REDUC];
};
struct P2 {
    Frag  w2[2 * 32 * 64];     // W2 B-frags (hi, then repacked lo) 64 KB
    float gall[32][REDUC];     // cummax'd g rows (20 valid + pad)   8 KB
    float b2s[DIM], g2s[DIM], be2s[DIM];
    float rsum[32][2], rvar[32][2];
};
union SMem { P1 p1; P2 p2; };

// Single fused kernel. Grid (14, 32), 256 threads.
// Phase 1 (all blocks): comp = LN(relu(x @ W1 + b1)) via bf16 MFMA; sampled
//   rows -> partials, local rows -> present (agent-scope coherent stores).
// Poison-absorbing ticket: the harness poisons ws to 0xAA before the first
//   call AND before timing. Every block first tries
//   atomicCAS(cnt, 0xAAAAAAAA, 1): in a poisoned call exactly one winner
//   consumes the poison (ticket 0); everyone else atomicInc-wraps at 13
//   (tickets 1..13). From a clean 0 start, all tickets come from atomicInc
//   (0..13). Either way ticket==13 is the TRUE 14th arrival -> all other
//   blocks' fenced stores are complete -> identical correct output on every
//   call; counter self-wraps to 0 for the next call.
// Phase 2 (trigger block): out = LN(relu(max(past,cummax(present)) @ W2 + b2))
//   via SPLIT-bf16 MFMA (A_hi*B_hi + A_lo*B_hi + A_hi*B_lo -> ~f32 precision).
__global__ __launch_bounds__(256) void fused(
        const float* __restrict__ obs,
        const float* __restrict__ W1, const float* __restrict__ b1,
        const float* __restrict__ g1, const float* __restrict__ beta1,
        const float* __restrict__ W2, const float* __restrict__ b2,
        const float* __restrict__ g2, const float* __restrict__ beta2,
        float* __restrict__ partials, float* __restrict__ present,
        unsigned* __restrict__ cnt, float* __restrict__ out)
{
    __shared__ SMem sm;
    __shared__ unsigned trig;

    const int t   = threadIdx.x;
    const int l   = t & 63;
    const int w   = __builtin_amdgcn_readfirstlane((int)(t >> 6));
    const int blk = blockIdx.x;
    const int b   = blockIdx.y;

    // ---------- phase 1a: issue all x loads first (HBM, long latency) ----
    const int s2s  = t >> 7;               // K-substep staged
    const int mts  = (t >> 6) & 1;         // M-tile staged
    const int rloc = 16 * mts + (l & 15);  // row staged
    int rr = blk * RPB + rloc;
    int rc = (rr < N_ROWS) ? rr : 0;       // clamp pad rows (discarded later)
    int tt = (rc < N_SAMP) ? rc * SR : (T_FULL - N_LOC) + (rc - N_SAMP);
    const float* xptr = obs + ((size_t)b * T_FULL + tt) * DIM
                        + 32 * s2s + 8 * (l >> 4);
    float4 xa[8], xb[8];
#pragma unroll
    for (int c = 0; c < 8; ++c) {
        xa[c] = *(const float4*)(xptr + 64 * c);
        xb[c] = *(const float4*)(xptr + 64 * c + 4);
    }

    // ---------- phase 1b: pack W1 (f32, L2-hot) -> LDS B-frags ----------
    // frag(sg,tile,lane): elem f = W1[32sg + 8(lane>>4) + f][16tile + (lane&15)]
    {
        const int sg = t >> 4, q = t & 15;
        const int tile = q >> 2, a = q & 3;          // a = lane>>4 group
#pragma unroll
        for (int c = 0; c < 4; ++c) {                // lane quad 16a+4c..+3
            float4 vf[8];
#pragma unroll
            for (int f = 0; f < 8; ++f)
                vf[f] = *(const float4*)(W1 + (size_t)(32*sg + 8*a + f) * REDUC
                                         + 16*tile + 4*c);
#pragma unroll
            for (int j = 0; j < 4; ++j) {
                Frag fr;
                fr.u.x = pack2(((float*)&vf[0])[j], ((float*)&vf[1])[j]);
                fr.u.y = pack2(((float*)&vf[2])[j], ((float*)&vf[3])[j]);
                fr.u.z = pack2(((float*)&vf[4])[j], ((float*)&vf[5])[j]);
                fr.u.w = pack2(((float*)&vf[6])[j], ((float*)&vf[7])[j]);
                sm.p1.w1[(sg * 4 + tile) * 64 + 16*a + 4*c + j] = fr;
            }
        }
    }

    // pack x -> A-frag LDS
#pragma unroll
    for (int c = 0; c < 8; ++c) {
        Frag fr;
        fr.u.x = pack2(xa[c].x, xa[c].y); fr.u.y = pack2(xa[c].z, xa[c].w);
        fr.u.z = pack2(xb[c].x, xb[c].y); fr.u.w = pack2(xb[c].z, xb[c].w);
        sm.p1.abuf[c][t] = fr;
    }
    __syncthreads();

    // ---------- phase 1c: MFMA 32x64 x-tile @ W1 ----------
    const int mt = w >> 1, nh = w & 1;
    {
        f32x4 acc0 = {0.f, 0.f, 0.f, 0.f};
        f32x4 acc1 = {0.f, 0.f, 0.f, 0.f};
#pragma unroll
        for (int c = 0; c < 8; ++c) {
#pragma unroll
            for (int s2 = 0; s2 < 2; ++s2) {
                Frag A; A.u = sm.p1.abuf[c][(s2 * 2 + mt) * 64 + l].u;
                const int sg = c * 2 + s2;
                Frag B0, B1;
                B0.u = sm.p1.w1[(sg * 4 + 2 * nh + 0) * 64 + l].u;
                B1.u = sm.p1.w1[(sg * 4 + 2 * nh + 1) * 64 + l].u;
                acc0 = __builtin_amdgcn_mfma_f32_16x16x32_bf16(A.v, B0.v, acc0, 0, 0, 0);
                acc1 = __builtin_amdgcn_mfma_f32_16x16x32_bf16(A.v, B1.v, acc1, 0, 0, 0);
            }
        }
        const int crow = 16 * mt + 4 * (l >> 4);
        const int ccol = 32 * nh + (l & 15);
#pragma unroll
        for (int r = 0; r < 4; ++r) {
            sm.p1.comp[crow + r][ccol]      = acc0[r];
            sm.p1.comp[crow + r][ccol + 16] = acc1[r];
        }
    }
    __syncthreads();

    // ---------- phase 1d: LN epilogue ----------
    const float g1v = g1[l], be1v = beta1[l], b1v = b1[l];
    float wmax = -INFINITY;
#pragma unroll
    for (int r8 = 0; r8 < 8; ++r8) {
        int rl  = w * 8 + r8;
        int rr2 = blk * RPB + rl;
        float y = fmaxf(sm.p1.comp[rl][l] + b1v, 0.f);
        float s = y;
#pragma unroll
        for (int off = 32; off >= 1; off >>= 1) s += __shfl_xor(s, off);
        float mu = s * (1.f / 64.f);
        float d  = y - mu;
        float v  = d * d;
#pragma unroll
        for (int off = 32; off >= 1; off >>= 1) v += __shfl_xor(v, off);
        float cres = d * rsqrtf(v * (1.f / 64.f) + EPS) * g1v + be1v;

        if (rr2 < N_SAMP) {
            wmax = fmaxf(wmax, cres);
        } else if (rr2 < N_ROWS) {
            coh_store(&present[((size_t)b * N_LOC + (rr2 - N_SAMP)) * REDUC + l], cres);
        }
    }
    sm.p1.pmax[w][l] = wmax;
    __syncthreads();
    if (w == 0 && blk < NPART) {
        float m = fmaxf(fmaxf(sm.p1.pmax[0][l], sm.p1.pmax[1][l]),
                        fmaxf(sm.p1.pmax[2][l], sm.p1.pmax[3][l]));
        coh_store(&partials[((size_t)b * NPART + blk) * REDUC + l], m);
    }

    // ---------- poison-absorbing ticket; trigger = true 14th arrival ----
    __threadfence();                        // release partials/present
    __syncthreads();
    if (t == 0) {
        unsigned old = atomicCAS(&cnt[b], POISON, 1u);
        unsigned tick;
        if (old == POISON) tick = 0u;       // consumed poison, arrival #0
        else tick = atomicInc(&cnt[b], (unsigned)(BPB - 1));
        trig = tick;
    }
    __syncthreads();
    if (trig != (unsigned)(BPB - 1)) return;
    __threadfence();                        // acquire others' writes

    // ---------- phase 2: out = LN(relu(g @ W2 + b2)) for this batch ----
    sm.p2.b2s[t]  = b2[t];    sm.p2.b2s[t + 256]  = b2[t + 256];
    sm.p2.g2s[t]  = g2[t];    sm.p2.g2s[t + 256]  = g2[t + 256];
    sm.p2.be2s[t] = beta2[t]; sm.p2.be2s[t + 256] = beta2[t + 256];
    // gall rows 0..19 = max(past partials, cummax(present)); rows 20..31 = 0
    if (t < REDUC) {
        float m = -INFINITY;
#pragma unroll
        for (int p = 0; p < NPART; ++p)
            m = fmaxf(m, coh_load(&partials[((size_t)b * NPART + p) * REDUC + t]));
        for (int s = 0; s < N_LOC; ++s) {
            m = fmaxf(m, coh_load(&present[((size_t)b * N_LOC + s) * REDUC + t]));
            sm.p2.gall[s][t] = m;
        }
    }
    for (int idx = t; idx < 12 * REDUC; idx += 256)
        ((float*)sm.p2.gall)[N_LOC * REDUC + idx] = 0.f;
    // pack W2_hi -> LDS B-frags: frag(sg2,tile,lane):
    //   W2[32sg2 + 8(l>>4) + f][16tile + (l&15)]
    const int sg2t = t >> 7, r7 = t & 127;
    const int tl2 = r7 >> 2, a2 = r7 & 3;
    {
#pragma unroll
        for (int c = 0; c < 4; ++c) {
            float4 vf[8];
#pragma unroll
            for (int f = 0; f < 8; ++f)
                vf[f] = *(const float4*)(W2 + (size_t)(32*sg2t + 8*a2 + f) * DIM
                                         + 16*tl2 + 4*c);
#pragma unroll
            for (int j = 0; j < 4; ++j) {
                Frag fr;
                fr.u.x = pack2(((float*)&vf[0])[j], ((float*)&vf[1])[j]);
                fr.u.y = pack2(((float*)&vf[2])[j], ((float*)&vf[3])[j]);
                fr.u.z = pack2(((float*)&vf[4])[j], ((float*)&vf[5])[j]);
                fr.u.w = pack2(((float*)&vf[6])[j], ((float*)&vf[7])[j]);
                sm.p2.w2[(sg2t * 32 + tl2) * 64 + 16*a2 + 4*c + j] = fr;
            }
        }
    }
    __syncthreads();

    // A-frags (hi + lo split) from gall; wave w: M-tile mt, N-half nh
    Frag afrh[2], afrl[2];
#pragma unroll
    for (int sg2 = 0; sg2 < 2; ++sg2) {
        const float* gp = &sm.p2.gall[16 * mt + (l & 15)][32 * sg2 + 8 * (l >> 4)];
        float4 ga = *(const float4*)gp;
        float4 gb = *(const float4*)(gp + 4);
        afrh[sg2].u.x = pack2(ga.x, ga.y);    afrh[sg2].u.y = pack2(ga.z, ga.w);
        afrh[sg2].u.z = pack2(gb.x, gb.y);    afrh[sg2].u.w = pack2(gb.z, gb.w);
        afrl[sg2].u.x = pack2_lo(ga.x, ga.y); afrl[sg2].u.y = pack2_lo(ga.z, ga.w);
        afrl[sg2].u.z = pack2_lo(gb.x, gb.y); afrl[sg2].u.w = pack2_lo(gb.z, gb.w);
    }
    f32x4 acc2[16];
#pragma unroll
    for (int tile = 0; tile < 16; ++tile) acc2[tile] = (f32x4){0.f, 0.f, 0.f, 0.f};
    // pass 1: A_hi@B_hi + A_lo@B_hi
#pragma unroll
    for (int tile = 0; tile < 16; ++tile)
#pragma unroll
        for (int sg2 = 0; sg2 < 2; ++sg2) {
            Frag B; B.u = sm.p2.w2[(sg2 * 32 + 16 * nh + tile) * 64 + l].u;
            acc2[tile] = __builtin_amdgcn_mfma_f32_16x16x32_bf16(afrh[sg2].v, B.v, acc2[tile], 0, 0, 0);
            acc2[tile] = __builtin_amdgcn_mfma_f32_16x16x32_bf16(afrl[sg2].v, B.v, acc2[tile], 0, 0, 0);
        }
    __syncthreads();                       // all waves done reading w2_hi
    // repack w2 buffer with W2_lo
    {
#pragma unroll
        for (int c = 0; c < 4; ++c) {
            float4 vf[8];
#pragma unroll
            for (int f = 0; f < 8; ++f)
                vf[f] = *(const float4*)(W2 + (size_t)(32*sg2t + 8*a2 + f) * DIM
                                         + 16*tl2 + 4*c);
#pragma unroll
            for (int j = 0; j < 4; ++j) {
                Frag fr;
                fr.u.x = pack2_lo(((float*)&vf[0])[j], ((float*)&vf[1])[j]);
                fr.u.y = pack2_lo(((float*)&vf[2])[j], ((float*)&vf[3])[j]);
                fr.u.z = pack2_lo(((float*)&vf[4])[j], ((float*)&vf[5])[j]);
                fr.u.w = pack2_lo(((float*)&vf[6])[j], ((float*)&vf[7])[j]);
                sm.p2.w2[(sg2t * 32 + tl2) * 64 + 16*a2 + 4*c + j] = fr;
            }
        }
    }
    __syncthreads();
    // pass 2: A_hi@B_lo
#pragma unroll
    for (int tile = 0; tile < 16; ++tile)
#pragma unroll
        for (int sg2 = 0; sg2 < 2; ++sg2) {
            Frag B; B.u = sm.p2.w2[(sg2 * 32 + 16 * nh + tile) * 64 + l].u;
            acc2[tile] = __builtin_amdgcn_mfma_f32_16x16x32_bf16(afrh[sg2].v, B.v, acc2[tile], 0, 0, 0);
        }

    // bias + relu, then LN over 512 cols per row (rows m = 16mt + 4(l>>4) + r)
    float rs[4] = {0.f, 0.f, 0.f, 0.f};
#pragma unroll
    for (int tile = 0; tile < 16; ++tile) {
        int j = 256 * nh + 16 * tile + (l & 15);
        float bv = sm.p2.b2s[j];
#pragma unroll
        for (int r = 0; r < 4; ++r) {
            float y = fmaxf(acc2[tile][r] + bv, 0.f);
            acc2[tile][r] = y;
            rs[r] += y;
        }
    }
#pragma unroll
    for (int r = 0; r < 4; ++r)
#pragma unroll
        for (int off = 1; off <= 8; off <<= 1) rs[r] += __shfl_xor(rs[r], off);
    if ((l & 15) == 0)
#pragma unroll
        for (int r = 0; r < 4; ++r)
            sm.p2.rsum[16 * mt + 4 * (l >> 4) + r][nh] = rs[r];
    __syncthreads();

    float mu4[4];
#pragma unroll
    for (int r = 0; r < 4; ++r) {
        int m = 16 * mt + 4 * (l >> 4) + r;
        mu4[r] = (sm.p2.rsum[m][0] + sm.p2.rsum[m][1]) * (1.f / 512.f);
    }
    float rv[4] = {0.f, 0.f, 0.f, 0.f};
#pragma unroll
    for (int tile = 0; tile < 16; ++tile)
#pragma unroll
        for (int r = 0; r < 4; ++r) {
            float d = acc2[tile][r] - mu4[r];
            rv[r] += d * d;
        }
#pragma unroll
    for (int r = 0; r < 4; ++r)
#pragma unroll
        for (int off = 1; off <= 8; off <<= 1) rv[r] += __shfl_xor(rv[r], off);
    if ((l & 15) == 0)
#pragma unroll
        for (int r = 0; r < 4; ++r)
            sm.p2.rvar[16 * mt + 4 * (l >> 4) + r][nh] = rv[r];
    __syncthreads();

#pragma unroll
    for (int tile = 0; tile < 16; ++tile) {
        int j = 256 * nh + 16 * tile + (l & 15);
        float g2v = sm.p2.g2s[j], be2v = sm.p2.be2s[j];
#pragma unroll
        for (int r = 0; r < 4; ++r) {
            int m = 16 * mt + 4 * (l >> 4) + r;
            if (m < N_LOC) {
                float var = (sm.p2.rvar[m][0] + sm.p2.rvar[m][1]) * (1.f / 512.f);
                float val = (acc2[tile][r] - mu4[r]) * rsqrtf(var + EPS) * g2v + be2v;
                out[((size_t)b * N_LOC + m) * DIM + j] = val;
            }
        }
    }
}

extern "C" void kernel_launch(void* const* d_in, const int* in_sizes, int n_in,
                              void* d_out, int out_size, void* d_ws, size_t ws_size,
                              hipStream_t stream) {
    const float* obs   = (const float*)d_in[0];
    const float* W1    = (const float*)d_in[1];
    const float* b1    = (const float*)d_in[2];
    const float* g1    = (const float*)d_in[3];
    const float* beta1 = (const float*)d_in[4];
    const float* W2    = (const float*)d_in[5];
    const float* b2    = (const float*)d_in[6];
    const float* g2    = (const float*)d_in[7];
    const float* beta2 = (const float*)d_in[8];
    float* out = (float*)d_out;

    // ws: partials [32][13][64] f32 | present [32][20][64] f32 | cnt [32] u32
    float*    partials = (float*)d_ws;
    float*    present  = partials + (size_t)NB * NPART * REDUC;
    unsigned* cnt      = (unsigned*)(present + (size_t)NB * N_LOC * REDUC);

    dim3 grid(BPB, NB);
    fused<<<grid, 256, 0, stream>>>(obs, W1, b1, g1, beta1, W2, b2, g2, beta2,
                                    partials, present, cnt, out);
}

// Round 12
// 30.721 us; speedup vs baseline: 3.9285x; 3.9285x over previous
//
#include <hip/hip_runtime.h>
#include <math.h>

#define DIM    512
#define REDUC  64
#define T_FULL 4096
#define NB     32
#define SR     10
#define N_SAMP 408     // t = 0,10,...,4070
#define N_LOC  20
#define N_ROWS 428     // per batch: 408 sampled + 20 local
#define EPS    1e-5f

#define RPB   32       // rows per block (2 M-tiles of 16)
#define BPB   14       // blocks per batch (block 13: 12 local-only rows)
#define NPART 13       // blocks containing sampled rows

typedef short bf16x8 __attribute__((ext_vector_type(8)));   // 8 bf16 in 4 VGPRs
typedef float f32x4  __attribute__((ext_vector_type(4)));

union Frag { bf16x8 v; uint4 u; };

__device__ __forceinline__ unsigned bf16_rne(float f) {     // round-nearest-even
    unsigned u = __float_as_uint(f);
    return (u + 0x7fffu + ((u >> 16) & 1u)) >> 16;
}
__device__ __forceinline__ unsigned pack2(float lo, float hi) {
    return bf16_rne(lo) | (bf16_rne(hi) << 16);
}

// k1: comp = LN(relu(x @ W1 + b1)) for the 428 needed rows per batch via
// bf16 MFMA 16x16x32. Block = 4 waves = 32 rows x 64 j. Wave w: M-tile w>>1,
// N-half w&1. K is processed in two halves of 256; per half the block packs
// that half of W1 (f32, L2-hot) into LDS B-frags (128 threads; r6-proven
// mapping) and its x chunk into LDS A-frags, then runs 16 MFMAs,
// accumulating across halves. All 16 x dwordx4 loads issued up front.
// LDS 57.3 KB -> 2 blocks/CU.
__global__ __launch_bounds__(256) void k1_rows(
        const float* __restrict__ obs, const float* __restrict__ W1,
        const float* __restrict__ b1, const float* __restrict__ g1,
        const float* __restrict__ beta1,
        float* __restrict__ partials, float* __restrict__ present)
{
    __shared__ Frag  w1h[8 * 4 * 64];      // 32 KB: one K-half of W1 B-frags
    __shared__ Frag  abuf[4][256];         // 16 KB: one K-half of x A-frags
    __shared__ float comp[RPB][66];        // 8.4 KB C tile (+2 pad)
    __shared__ float pmax[4][REDUC];       // 1 KB

    const int t   = threadIdx.x;
    const int l   = t & 63;
    const int w   = __builtin_amdgcn_readfirstlane((int)(t >> 6));
    const int blk = blockIdx.x;
    const int b   = blockIdx.y;

    // staging geometry (r5): thread t -> chunk slot (s2s*2 + mts)*64 + l
    const int s2s  = t >> 7;               // K-substep staged
    const int mts  = (t >> 6) & 1;         // M-tile staged
    const int rloc = 16 * mts + (l & 15);  // row staged
    int rr = blk * RPB + rloc;
    int rc = (rr < N_ROWS) ? rr : 0;       // clamp pad rows (discarded later)
    int tt = (rc < N_SAMP) ? rc * SR : (T_FULL - N_LOC) + (rc - N_SAMP);
    const float* xptr = obs + ((size_t)b * T_FULL + tt) * DIM
                        + 32 * s2s + 8 * (l >> 4);

    // issue ALL x loads up front (16 dwordx4/thread in flight)
    float4 xa[8], xb[8];
#pragma unroll
    for (int c = 0; c < 8; ++c) {
        xa[c] = *(const float4*)(xptr + 64 * c);
        xb[c] = *(const float4*)(xptr + 64 * c + 4);
    }

    // W1-pack job (r6 mapping): thread t owns sg = t>>4, tile = (t&15)>>2,
    // a = t&3; writes 16 frags (4 c-groups x 4 lanes). Active in half sg>>3.
    const int sgW  = t >> 4;               // global K-step 0..15
    const int tlW  = (t & 15) >> 2;
    const int aW   = t & 3;

    const int mt = w >> 1, nh = w & 1;
    f32x4 acc0 = {0.f, 0.f, 0.f, 0.f};
    f32x4 acc1 = {0.f, 0.f, 0.f, 0.f};

    for (int h = 0; h < 2; ++h) {
        if (h) __syncthreads();            // previous half's MFMAs done
        // pack x chunks of this half -> A-frags
#pragma unroll
        for (int c4 = 0; c4 < 4; ++c4) {
            const int c = 4 * h + c4;
            Frag fr;
            fr.u.x = pack2(xa[c].x, xa[c].y); fr.u.y = pack2(xa[c].z, xa[c].w);
            fr.u.z = pack2(xb[c].x, xb[c].y); fr.u.w = pack2(xb[c].z, xb[c].w);
            abuf[c4][t] = fr;
        }
        // pack this half of W1 -> B-frags (threads with sg in this half)
        if ((sgW >> 3) == h) {
            const int sgl = sgW & 7;
#pragma unroll
            for (int c = 0; c < 4; ++c) {
                float4 vf[8];
#pragma unroll
                for (int f = 0; f < 8; ++f)
                    vf[f] = *(const float4*)(W1 + (size_t)(32*sgW + 8*aW + f) * REDUC
                                             + 16*tlW + 4*c);
#pragma unroll
                for (int j = 0; j < 4; ++j) {
                    Frag fr;
                    fr.u.x = pack2(((float*)&vf[0])[j], ((float*)&vf[1])[j]);
                    fr.u.y = pack2(((float*)&vf[2])[j], ((float*)&vf[3])[j]);
                    fr.u.z = pack2(((float*)&vf[4])[j], ((float*)&vf[5])[j]);
                    fr.u.w = pack2(((float*)&vf[6])[j], ((float*)&vf[7])[j]);
                    w1h[(sgl * 4 + tlW) * 64 + 16*aW + 4*c + j] = fr;
                }
            }
        }
        __syncthreads();
        // MFMA: 8 K-steps of this half
#pragma unroll
        for (int c4 = 0; c4 < 4; ++c4) {
#pragma unroll
            for (int s2 = 0; s2 < 2; ++s2) {
                const int sgl = c4 * 2 + s2;
                Frag A; A.u = abuf[c4][(s2 * 2 + mt) * 64 + l].u;
                Frag B0, B1;
                B0.u = w1h[(sgl * 4 + 2 * nh + 0) * 64 + l].u;
                B1.u = w1h[(sgl * 4 + 2 * nh + 1) * 64 + l].u;
                acc0 = __builtin_amdgcn_mfma_f32_16x16x32_bf16(A.v, B0.v, acc0, 0, 0, 0);
                acc1 = __builtin_amdgcn_mfma_f32_16x16x32_bf16(A.v, B1.v, acc1, 0, 0, 0);
            }
        }
    }

    // write C: D[m=(l>>4)*4+reg][n=l&15] per 16x16 tile
    const int crow = 16 * mt + 4 * (l >> 4);
    const int ccol = 32 * nh + (l & 15);
#pragma unroll
    for (int r = 0; r < 4; ++r) {
        comp[crow + r][ccol]      = acc0[r];
        comp[crow + r][ccol + 16] = acc1[r];
    }
    __syncthreads();

    // LN epilogue: wave w owns rows 8w..8w+7; lane l = output dim j
    const float g1v = g1[l], be1v = beta1[l], b1v = b1[l];
    float wmax = -INFINITY;
#pragma unroll
    for (int r8 = 0; r8 < 8; ++r8) {
        int rl  = w * 8 + r8;
        int rr2 = blk * RPB + rl;
        float y = fmaxf(comp[rl][l] + b1v, 0.f);
        float s = y;
#pragma unroll
        for (int off = 32; off >= 1; off >>= 1) s += __shfl_xor(s, off);
        float mu = s * (1.f / 64.f);
        float d  = y - mu;
        float v  = d * d;
#pragma unroll
        for (int off = 32; off >= 1; off >>= 1) v += __shfl_xor(v, off);
        float cres = d * rsqrtf(v * (1.f / 64.f) + EPS) * g1v + be1v;

        if (rr2 < N_SAMP) {
            wmax = fmaxf(wmax, cres);
        } else if (rr2 < N_ROWS) {
            present[((size_t)b * N_LOC + (rr2 - N_SAMP)) * REDUC + l] = cres;
        }
    }

    pmax[w][l] = wmax;
    __syncthreads();
    if (w == 0 && blk < NPART) {
        float m = fmaxf(fmaxf(pmax[0][l], pmax[1][l]),
                        fmaxf(pmax[2][l], pmax[3][l]));
        partials[((size_t)b * NPART + blk) * REDUC + l] = m;
    }
}

// k2: per (batch, local-step): g = max(partials, cummax(present[0..t]));
// out = LN(relu(g @ W2 + b2)). 512 threads; max phase parallel over 8 slices.
__global__ __launch_bounds__(512) void k2_out(
        const float* __restrict__ partials,
        const float* __restrict__ present,
        const float* __restrict__ W2, const float* __restrict__ b2,
        const float* __restrict__ g2, const float* __restrict__ beta2,
        float* __restrict__ out)
{
    __shared__ float msh[8][REDUC];
    __shared__ float gsh[REDUC];
    __shared__ float red[16];

    const int b   = blockIdx.x / N_LOC;
    const int t   = blockIdx.x % N_LOC;
    const int tid = threadIdx.x;
    const int j   = tid & 63;
    const int s8  = tid >> 6;

    float m = -INFINITY;
    for (int p = s8; p < NPART; p += 8)
        m = fmaxf(m, partials[((size_t)b * NPART + p) * REDUC + j]);
    for (int r = s8; r <= t; r += 8)
        m = fmaxf(m, present[((size_t)b * N_LOC + r) * REDUC + j]);
    msh[s8][j] = m;
    __syncthreads();
    if (tid < REDUC) {
        float mm = msh[0][tid];
#pragma unroll
        for (int ss = 1; ss < 8; ++ss) mm = fmaxf(mm, msh[ss][tid]);
        gsh[tid] = mm;
    }
    __syncthreads();

    float acc = b2[tid];
#pragma unroll 8
    for (int k = 0; k < REDUC; ++k)
        acc = fmaf(gsh[k], W2[k * DIM + tid], acc);
    float y = fmaxf(acc, 0.f);

    const int lane = tid & 63, wv = tid >> 6;
    float s = y;
#pragma unroll
    for (int off = 32; off >= 1; off >>= 1) s += __shfl_xor(s, off);
    if (lane == 0) red[wv] = s;
    __syncthreads();
    float tot = red[0] + red[1] + red[2] + red[3] +
                red[4] + red[5] + red[6] + red[7];
    float mu = tot * (1.f / 512.f);
    float d  = y - mu;

    float v = d * d;
#pragma unroll
    for (int off = 32; off >= 1; off >>= 1) v += __shfl_xor(v, off);
    if (lane == 0) red[8 + wv] = v;
    __syncthreads();
    float vtot = red[8] + red[9] + red[10] + red[11] +
                 red[12] + red[13] + red[14] + red[15];
    float var = vtot * (1.f / 512.f);

    out[((size_t)b * N_LOC + t) * DIM + tid] =
        d * rsqrtf(var + EPS) * g2[tid] + beta2[tid];
}

extern "C" void kernel_launch(void* const* d_in, const int* in_sizes, int n_in,
                              void* d_out, int out_size, void* d_ws, size_t ws_size,
                              hipStream_t stream) {
    const float* obs   = (const float*)d_in[0];
    const float* W1    = (const float*)d_in[1];
    const float* b1    = (const float*)d_in[2];
    const float* g1    = (const float*)d_in[3];
    const float* beta1 = (const float*)d_in[4];
    const float* W2    = (const float*)d_in[5];
    const float* b2    = (const float*)d_in[6];
    const float* g2    = (const float*)d_in[7];
    const float* beta2 = (const float*)d_in[8];
    float* out = (float*)d_out;

    // ws: partials [32][13][64] f32 | present [32][20][64] f32
    float* partials = (float*)d_ws;
    float* present  = partials + (size_t)NB * NPART * REDUC;

    dim3 g1d(BPB, NB);
    k1_rows<<<g1d, 256, 0, stream>>>(obs, W1, b1, g1, beta1, partials, present);
    k2_out<<<NB * N_LOC, 512, 0, stream>>>(partials, present, W2, b2, g2, beta2, out);
}